// Round 9
// baseline (7581.642 us; speedup 1.0000x reference)
//
#include <hip/hip_runtime.h>
#include <hip/hip_fp16.h>

// GRU 2-layer, B=256 S=1024 F=75 H=256.
// Round 9: R8 + async early-issue gathers. Tags make the exchange self-
//  validating, so gather loads are issued immediately after each publish
//  (h0-gather before the L1 MFMA section, h1-gather right after h1 publish),
//  ride in VGPRs across compute, and are validated (min-tag) at phase end.
//  Stale/spilled registers degrade to R8's blocking retry, never corruption.
//  x[t+1] LDS-staging moved before S1 so no compiler vmem-waits land inside
//  the async window.

#define NS 1024
#define NF 75
#define NH 256

#define W0S 360   // halves: 96(x pad) + 256(h) + 8 pad
#define W1S 520   // 256(h0) + 256(h1) + 8 pad
#define HCS 520   // hcat row halves
#define XSS 104   // 96 + 8 pad

#define W0_HALVES (48 * W0S)                 // 17280
#define W1_HALVES (48 * W1S)                 // 24960
#define IMG_HALVES (W0_HALVES + W1_HALVES)   // 42240 halves = 84480 B

// shared aliasing offsets (bytes): loop structs overlay the weight staging area
#define HCAT_OFF 0          // 16*520*2 = 16640
#define XS_OFF   16640      // 2*16*104*2 = 6656 -> 23296
#define CT_OFF   23296      // 8*64*4*4  = 8192 -> 31488
#define RED_OFF  31488      // 16*17*4   = 1088 -> 32576  (< 84480)

// d_ws layout (bytes)
#define WIMG_OFF 0
#define WIMG_BYTES (16 * IMG_HALVES * 2)     // 1,351,680 (16B-aligned)
#define HX0_OFF WIMG_BYTES
#define HX_WORDS (2 * 16 * 16 * 256)         // u32 per array (2 parities)
#define HX1_OFF (HX0_OFF + HX_WORDS * 4)
#define HX_TOTAL_BYTES (2 * HX_WORDS * 4)    // 1 MiB

typedef _Float16 f16x8 __attribute__((ext_vector_type(8)));
typedef float f32x4 __attribute__((ext_vector_type(4)));
typedef unsigned int u32x4 __attribute__((ext_vector_type(4)));

#define PINV(x) asm volatile("" : "+v"(x))

// MALL-routed coherent ops (sc0 sc1): placement-independent (R4..R8-proven)
__device__ __forceinline__ void st_u32_sys(unsigned* p, unsigned v) {
  asm volatile("global_store_dword %0, %1, off sc0 sc1" :: "v"(p), "v"(v) : "memory");
}
// async issue: NO waitcnt — values land later; consumer pins + waits.
__device__ __forceinline__ void issue4_sys(const unsigned* p, u32x4& a, u32x4& b,
                                           u32x4& c, u32x4& d) {
  asm volatile(
      "global_load_dwordx4 %0, %4, off sc0 sc1\n\t"
      "global_load_dwordx4 %1, %4, off offset:16 sc0 sc1\n\t"
      "global_load_dwordx4 %2, %4, off offset:32 sc0 sc1\n\t"
      "global_load_dwordx4 %3, %4, off offset:48 sc0 sc1"
      : "=&v"(a), "=&v"(b), "=&v"(c), "=&v"(d)
      : "v"(p) : "memory");
}
// blocking reload (retry path)
__device__ __forceinline__ void ld_2rows_sys(const unsigned* p0, const unsigned* p1,
    u32x4& a0, u32x4& a1, u32x4& a2, u32x4& a3,
    u32x4& b0, u32x4& b1, u32x4& b2, u32x4& b3) {
  asm volatile(
      "global_load_dwordx4 %0, %8, off sc0 sc1\n\t"
      "global_load_dwordx4 %1, %8, off offset:16 sc0 sc1\n\t"
      "global_load_dwordx4 %2, %8, off offset:32 sc0 sc1\n\t"
      "global_load_dwordx4 %3, %8, off offset:48 sc0 sc1\n\t"
      "global_load_dwordx4 %4, %9, off sc0 sc1\n\t"
      "global_load_dwordx4 %5, %9, off offset:16 sc0 sc1\n\t"
      "global_load_dwordx4 %6, %9, off offset:32 sc0 sc1\n\t"
      "global_load_dwordx4 %7, %9, off offset:48 sc0 sc1\n\t"
      "s_waitcnt vmcnt(0)"
      : "=&v"(a0), "=&v"(a1), "=&v"(a2), "=&v"(a3),
        "=&v"(b0), "=&v"(b1), "=&v"(b2), "=&v"(b3)
      : "v"(p0), "v"(p1) : "memory");
}

// Weight image per block j (halves): W0 [48][W0S] (x cols 0..74, h cols 96..351),
// W1 [48][W1S] (h0 cols 0..255, h1 cols 256..511); row = gate*16+u.
__global__ void prep_wimg(const float* __restrict__ wih0, const float* __restrict__ whh0,
                          const float* __restrict__ wih1, const float* __restrict__ whh1,
                          _Float16* __restrict__ wimg) {
  const int total = 16 * IMG_HALVES;
  for (int i = blockIdx.x * blockDim.x + threadIdx.x; i < total;
       i += gridDim.x * blockDim.x) {
    const int j = i / IMG_HALVES;
    int rem = i - j * IMG_HALVES;
    float val = 0.f;
    if (rem < W0_HALVES) {
      const int row = rem / W0S, k = rem - row * W0S;
      const int gate = row >> 4, u = row & 15;
      const int grow = gate * NH + j * 16 + u;
      if (k < NF) val = wih0[grow * NF + k];
      else if (k >= 96 && k < 352) val = whh0[grow * NH + (k - 96)];
    } else {
      rem -= W0_HALVES;
      const int row = rem / W1S, k = rem - row * W1S;
      const int gate = row >> 4, u = row & 15;
      const int grow = gate * NH + j * 16 + u;
      if (k < 256) val = wih1[grow * NH + k];
      else if (k < 512) val = whh1[grow * NH + (k - 256)];
    }
    wimg[i] = (_Float16)val;
  }
}

__global__ __launch_bounds__(256, 1) void gru_mfma(
    const float* __restrict__ x,
    const float* __restrict__ b_ih0, const float* __restrict__ b_hh0,
    const float* __restrict__ b_ih1, const float* __restrict__ b_hh1,
    const float* __restrict__ w_lin, const float* __restrict__ b_lin,
    const _Float16* __restrict__ wimg,
    unsigned* __restrict__ hx0, unsigned* __restrict__ hx1,
    float* __restrict__ out)
{
  const int tid = threadIdx.x;
  const int bid = blockIdx.x;
  const int gr = (bid & 7) + ((bid >> 7) << 3);   // grouping heuristic (perf-only)
  const int j  = (bid >> 3) & 15;

  __shared__ f16x8 smem8[IMG_HALVES / 8];          // 84480 B, aliased region
  _Float16* Wst  = (_Float16*)smem8;
  _Float16* hcat = (_Float16*)((char*)smem8 + HCAT_OFF);
  _Float16* xs   = (_Float16*)((char*)smem8 + XS_OFF);
  float (*ctile)[64][4] = (float(*)[64][4])((char*)smem8 + CT_OFF);
  float (*red)[17]      = (float(*)[17])((char*)smem8 + RED_OFF);

  int dead = 0, spins = 0;

  // ---- stage weight image into LDS ----
  {
    const float4* src = (const float4*)(wimg + (size_t)j * IMG_HALVES);
    float4* dst = (float4*)Wst;
    for (int i = tid; i < IMG_HALVES / 8; i += 256) dst[i] = src[i];
  }

  const int row = tid >> 4, u = tid & 15, gu = j * 16 + u;
  const int wid = tid >> 6, lane = tid & 63;
  const int lrow = lane & 15, lko = (lane >> 4) * 8;

  const float br0 = b_ih0[gu] + b_hh0[gu];
  const float bz0 = b_ih0[NH + gu] + b_hh0[NH + gu];
  const float bnx0 = b_ih0[2 * NH + gu], bnh0 = b_hh0[2 * NH + gu];
  const float br1 = b_ih1[gu] + b_hh1[gu];
  const float bz1 = b_ih1[NH + gu] + b_hh1[NH + gu];
  const float bnx1 = b_ih1[2 * NH + gu], bnh1 = b_hh1[2 * NH + gu];

  __syncthreads();   // Sa: weight image staged

  // ---- hoist loop-invariant B-fragments to VGPRs ----
  _Float16* W0s = Wst;
  _Float16* W1s = Wst + W0_HALVES;
  f16x8 Bw[11], Bn[16];
  if (wid == 0) {            // L0-r (ct0) + L1-nx (ct6)
    const _Float16* wb = W0s + lrow * W0S + lko;
    #pragma unroll
    for (int i = 0; i < 11; ++i) { Bw[i] = *(const f16x8*)(wb + i * 32); PINV(Bw[i]); }
    const _Float16* wn = W1s + (32 + lrow) * W1S + lko;
    #pragma unroll
    for (int i = 0; i < 8; ++i) { Bn[i] = *(const f16x8*)(wn + i * 32); PINV(Bn[i]); }
  } else if (wid == 1) {     // L0-z (ct1) + L1-nh (ct7)
    const _Float16* wb = W0s + (16 + lrow) * W0S + lko;
    #pragma unroll
    for (int i = 0; i < 11; ++i) { Bw[i] = *(const f16x8*)(wb + i * 32); PINV(Bw[i]); }
    const _Float16* wn = W1s + (32 + lrow) * W1S + lko;
    #pragma unroll
    for (int i = 0; i < 8; ++i) { Bn[i] = *(const f16x8*)(wn + (8 + i) * 32); PINV(Bn[i]); }
  } else if (wid == 2) {     // L0-nx (ct2) + L1-r (ct4)
    const _Float16* wb = W0s + (32 + lrow) * W0S + lko;
    #pragma unroll
    for (int i = 0; i < 3; ++i) { Bw[i] = *(const f16x8*)(wb + i * 32); PINV(Bw[i]); }
    const _Float16* wn = W1s + lrow * W1S + lko;
    #pragma unroll
    for (int i = 0; i < 16; ++i) { Bn[i] = *(const f16x8*)(wn + i * 32); PINV(Bn[i]); }
  } else {                   // L0-nh (ct3) + L1-z (ct5)
    const _Float16* wb = W0s + (32 + lrow) * W0S + lko;
    #pragma unroll
    for (int i = 0; i < 8; ++i) { Bw[i] = *(const f16x8*)(wb + (3 + i) * 32); PINV(Bw[i]); }
    const _Float16* wn = W1s + (16 + lrow) * W1S + lko;
    #pragma unroll
    for (int i = 0; i < 16; ++i) { Bn[i] = *(const f16x8*)(wn + i * 32); PINV(Bn[i]); }
  }
  __syncthreads();   // Sb: hoist reads done — weight bytes may now be clobbered

  // ---- init loop structs OVER the weight region ----
  for (int i = tid; i < 16 * HCS; i += 256) hcat[i] = (_Float16)0.f;
  for (int i = tid; i < 2 * 16 * XSS; i += 256) xs[i] = (_Float16)0.f;

  int xr_[5], xc_[5]; bool xv_[5];
  #pragma unroll
  for (int i = 0; i < 5; ++i) {
    const int idx = i * 256 + tid;
    xv_[i] = idx < 16 * NF;
    xr_[i] = xv_[i] ? idx / NF : 0;
    xc_[i] = xv_[i] ? idx % NF : 0;
  }
  const float* __restrict__ xbase = x + (size_t)(gr * 16) * NS * NF;
  #pragma unroll
  for (int i = 0; i < 5; ++i)
    if (xv_[i]) xs[xr_[i] * XSS + xc_[i]] =
        (_Float16)xbase[(size_t)xr_[i] * NS * NF + xc_[i]];

  float h0f = 0.f, h1f = 0.f;
  __syncthreads();   // Sc: hcat/xs(t=0) ready

  for (int p = 0; p <= NS; ++p) {
    const int par = p & 1;
    const unsigned tg = (unsigned)(p + 1);
    const int mj = tid & 15, rr = tid >> 4;
    const int off = par * 65536 + gr * 4096 + rr * 256 + mj * 16;

    // 1. next-x prefetch
    float xf[5];
    if (p + 1 < NS) {
      #pragma unroll
      for (int i = 0; i < 5; ++i)
        if (xv_[i]) xf[i] = xbase[((size_t)xr_[i] * NS + (p + 1)) * NF + xc_[i]];
    }

    // 2. A-fragments from LDS
    const _Float16* __restrict__ xp = xs + par * (16 * XSS) + lrow * XSS + lko;
    const _Float16* __restrict__ hp = hcat + lrow * HCS + lko;
    f16x8 xa0{}, xa1{}, xa2{};
    if (wid != 3) {
      xa0 = *(const f16x8*)(xp);
      xa1 = *(const f16x8*)(xp + 32);
      xa2 = *(const f16x8*)(xp + 64);
    }
    f16x8 hfr[16];
    #pragma unroll
    for (int kb = 0; kb < 8; ++kb) hfr[kb] = *(const f16x8*)(hp + kb * 32);
    if (wid != 0) {
      #pragma unroll
      for (int kb = 8; kb < 16; ++kb) hfr[kb] = *(const f16x8*)(hp + kb * 32);
    }

    // 3. L0 MFMA tiles (ct0..3)
    {
      f32x4 accA = {0.f, 0.f, 0.f, 0.f};
      if (wid <= 1) {
        accA = __builtin_amdgcn_mfma_f32_16x16x32_f16(xa0, Bw[0], accA, 0, 0, 0);
        accA = __builtin_amdgcn_mfma_f32_16x16x32_f16(xa1, Bw[1], accA, 0, 0, 0);
        accA = __builtin_amdgcn_mfma_f32_16x16x32_f16(xa2, Bw[2], accA, 0, 0, 0);
        #pragma unroll
        for (int kb = 0; kb < 8; ++kb)
          accA = __builtin_amdgcn_mfma_f32_16x16x32_f16(hfr[kb], Bw[3 + kb], accA, 0, 0, 0);
        *(f32x4*)&ctile[wid][lane][0] = accA;
      } else if (wid == 2) {
        accA = __builtin_amdgcn_mfma_f32_16x16x32_f16(xa0, Bw[0], accA, 0, 0, 0);
        accA = __builtin_amdgcn_mfma_f32_16x16x32_f16(xa1, Bw[1], accA, 0, 0, 0);
        accA = __builtin_amdgcn_mfma_f32_16x16x32_f16(xa2, Bw[2], accA, 0, 0, 0);
        *(f32x4*)&ctile[2][lane][0] = accA;
      } else {
        #pragma unroll
        for (int kb = 0; kb < 8; ++kb)
          accA = __builtin_amdgcn_mfma_f32_16x16x32_f16(hfr[kb], Bw[kb], accA, 0, 0, 0);
        *(f32x4*)&ctile[3][lane][0] = accA;
      }
    }

    // 3.5 stage x[t+1] NOW (consume xf before the async window opens)
    if (p + 1 < NS) {
      #pragma unroll
      for (int i = 0; i < 5; ++i)
        if (xv_[i]) xs[((p + 1) & 1) * (16 * XSS) + xr_[i] * XSS + xc_[i]] =
            (_Float16)xf[i];
    }
    __syncthreads();  // S1: ct0..3 ready; all hcat/xs(par) reads done

    // 4. h0 gate + tagged publish + ASYNC h0-gather issue
    const int li = ((row >> 2) << 4) | u, rg = row & 3;
    if (p < NS) {
      const float ar = ctile[0][li][rg] + br0;
      const float az = ctile[1][li][rg] + bz0;
      const float nx = ctile[2][li][rg] + bnx0;
      const float nh = ctile[3][li][rg] + bnh0;
      const float r = 1.f / (1.f + __expf(-ar));
      const float z = 1.f / (1.f + __expf(-az));
      const float n = tanhf(nx + r * nh);
      h0f = (1.f - z) * n + z * h0f;
    }
    u32x4 A0, A1, A2, A3, B0, B1, B2, B3;
    {
      union { _Float16 h; unsigned short s; } c; c.h = (_Float16)h0f;
      st_u32_sys(hx0 + par * 65536 + gr * 4096 + row * 256 + gu,
                 (unsigned)c.s | (tg << 16));
      issue4_sys(hx0 + off, A0, A1, A2, A3);   // latency hides under L1 MFMA
    }

    // 5. L1 MFMA tiles (ct4..7)
    {
      f32x4 accB = {0.f, 0.f, 0.f, 0.f};
      if (wid == 0) {
        #pragma unroll
        for (int kb = 0; kb < 8; ++kb)
          accB = __builtin_amdgcn_mfma_f32_16x16x32_f16(hfr[kb], Bn[kb], accB, 0, 0, 0);
        *(f32x4*)&ctile[6][lane][0] = accB;
      } else if (wid == 1) {
        #pragma unroll
        for (int kb = 0; kb < 8; ++kb)
          accB = __builtin_amdgcn_mfma_f32_16x16x32_f16(hfr[8 + kb], Bn[kb], accB, 0, 0, 0);
        *(f32x4*)&ctile[7][lane][0] = accB;
      } else {
        #pragma unroll
        for (int kb = 0; kb < 16; ++kb)
          accB = __builtin_amdgcn_mfma_f32_16x16x32_f16(hfr[kb], Bn[kb], accB, 0, 0, 0);
        *(f32x4*)&ctile[2 + wid][lane][0] = accB;   // wid2->4, wid3->5
      }
    }
    __syncthreads();  // S2: ct4..7 ready

    // 6. h1 gate + tagged publish + ASYNC h1-gather issue
    if (p >= 1) {
      const float ar = ctile[4][li][rg] + br1;
      const float az = ctile[5][li][rg] + bz1;
      const float nx = ctile[6][li][rg] + bnx1;
      const float nh = ctile[7][li][rg] + bnh1;
      const float r = 1.f / (1.f + __expf(-ar));
      const float z = 1.f / (1.f + __expf(-az));
      const float n = tanhf(nx + r * nh);
      h1f = (1.f - z) * n + z * h1f;
    }
    {
      union { _Float16 h; unsigned short s; } c; c.h = (_Float16)h1f;
      st_u32_sys(hx1 + par * 65536 + gr * 4096 + row * 256 + gu,
                 (unsigned)c.s | (tg << 16));
      issue4_sys(hx1 + off, B0, B1, B2, B3);
    }

    // 8. pin + wait + validate; rare-retry blocking; unpack to hcat
    {
      asm volatile("s_waitcnt vmcnt(0)"
                   : "+v"(A0), "+v"(A1), "+v"(A2), "+v"(A3),
                     "+v"(B0), "+v"(B1), "+v"(B2), "+v"(B3) :: "memory");
      for (;;) {
        u32x4 m4 = __builtin_elementwise_min(
            __builtin_elementwise_min(__builtin_elementwise_min(A0, A1),
                                      __builtin_elementwise_min(A2, A3)),
            __builtin_elementwise_min(__builtin_elementwise_min(B0, B1),
                                      __builtin_elementwise_min(B2, B3)));
        unsigned m = m4.x;
        m = m4.y < m ? m4.y : m;
        m = m4.z < m ? m4.z : m;
        m = m4.w < m ? m4.w : m;
        if ((m >> 16) == tg) break;          // all 32 tags fresh
        if (++spins > 200000) { dead = 1; break; }
        __builtin_amdgcn_s_sleep(1);
        ld_2rows_sys(hx0 + off, hx1 + off, A0, A1, A2, A3, B0, B1, B2, B3);
      }
      _Float16* h0d = hcat + rr * HCS + mj * 16;
      _Float16* h1d = h0d + 256;
      *(unsigned*)(h0d + 0)  = (A0.x & 0xffffu) | (A0.y << 16);
      *(unsigned*)(h0d + 2)  = (A0.z & 0xffffu) | (A0.w << 16);
      *(unsigned*)(h0d + 4)  = (A1.x & 0xffffu) | (A1.y << 16);
      *(unsigned*)(h0d + 6)  = (A1.z & 0xffffu) | (A1.w << 16);
      *(unsigned*)(h0d + 8)  = (A2.x & 0xffffu) | (A2.y << 16);
      *(unsigned*)(h0d + 10) = (A2.z & 0xffffu) | (A2.w << 16);
      *(unsigned*)(h0d + 12) = (A3.x & 0xffffu) | (A3.y << 16);
      *(unsigned*)(h0d + 14) = (A3.z & 0xffffu) | (A3.w << 16);
      *(unsigned*)(h1d + 0)  = (B0.x & 0xffffu) | (B0.y << 16);
      *(unsigned*)(h1d + 2)  = (B0.z & 0xffffu) | (B0.w << 16);
      *(unsigned*)(h1d + 4)  = (B1.x & 0xffffu) | (B1.y << 16);
      *(unsigned*)(h1d + 6)  = (B1.z & 0xffffu) | (B1.w << 16);
      *(unsigned*)(h1d + 8)  = (B2.x & 0xffffu) | (B2.y << 16);
      *(unsigned*)(h1d + 10) = (B2.z & 0xffffu) | (B2.w << 16);
      *(unsigned*)(h1d + 12) = (B3.x & 0xffffu) | (B3.y << 16);
      *(unsigned*)(h1d + 14) = (B3.z & 0xffffu) | (B3.w << 16);
    }
    __syncthreads();  // S4: hcat ready for next phase
  }

  // ---- final linear ----
  {
    float part = 0.f;
    #pragma unroll
    for (int e = 0; e < 16; ++e)
      part += (float)hcat[row * HCS + 256 + u * 16 + e] * w_lin[u * 16 + e];
    red[row][u] = part;
    __syncthreads();
    if (j == 0 && tid < 16) {
      float s = 0.f;
      #pragma unroll
      for (int e = 0; e < 16; ++e) s += red[tid][e];
      out[gr * 16 + tid] = s + b_lin[0];
    }
  }
}

extern "C" void kernel_launch(void* const* d_in, const int* in_sizes, int n_in,
                              void* d_out, int out_size, void* d_ws, size_t ws_size,
                              hipStream_t stream) {
  (void)in_sizes; (void)n_in; (void)out_size; (void)ws_size;
  const float* x     = (const float*)d_in[0];
  const float* w_ih0 = (const float*)d_in[1];
  const float* w_hh0 = (const float*)d_in[2];
  const float* b_ih0 = (const float*)d_in[3];
  const float* b_hh0 = (const float*)d_in[4];
  const float* w_ih1 = (const float*)d_in[5];
  const float* w_hh1 = (const float*)d_in[6];
  const float* b_ih1 = (const float*)d_in[7];
  const float* b_hh1 = (const float*)d_in[8];
  const float* w_lin = (const float*)d_in[9];
  const float* b_lin = (const float*)d_in[10];

  char* ws = (char*)d_ws;
  _Float16* wimg = (_Float16*)(ws + WIMG_OFF);
  unsigned* hx0  = (unsigned*)(ws + HX0_OFF);
  unsigned* hx1  = (unsigned*)(ws + HX1_OFF);

  hipMemsetAsync(ws + HX0_OFF, 0, HX_TOTAL_BYTES, stream);
  prep_wimg<<<1024, 256, 0, stream>>>(w_ih0, w_hh0, w_ih1, w_hh1, wimg);
  gru_mfma<<<256, 256, 0, stream>>>(x, b_ih0, b_hh0, b_ih1, b_hh1,
                                    w_lin, b_lin, wimg, hx0, hx1,
                                    (float*)d_out);
}

// Round 10
// 2860.649 us; speedup vs baseline: 2.6503x; 2.6503x over previous
//
#include <hip/hip_runtime.h>
#include <hip/hip_fp16.h>

// GRU 2-layer, B=256 S=1024 F=75 H=256.
// Round 10: split-wait exchange. h1[p-2] gathered at phase start (published a
//  full phase ago -> always fresh), validated mid-phase; h0[p] published ~40%
//  into the phase, validated at phase end (age ~60%). ct4/ct5 K-split across
//  the mid barrier (h0-part pre, h1-part post; acc carried in regs). Barriers
//  are raw s_barrier + lgkmcnt(0) ONLY (no vmcnt drain -> gathers stay async;
//  tags make any visibility race a retry, never corruption).

#define NS 1024
#define NF 75
#define NH 256

#define W0S 360   // halves: 96(x pad) + 256(h) + 8 pad
#define W1S 520   // 256(h0) + 256(h1) + 8 pad
#define HCS 520   // hcat row halves: [h0 0..255 | h1 256..511] + pad
#define XSS 104   // 96 + 8 pad

#define W0_HALVES (48 * W0S)                 // 17280
#define W1_HALVES (48 * W1S)                 // 24960
#define IMG_HALVES (W0_HALVES + W1_HALVES)   // 42240 halves = 84480 B

// shared aliasing offsets (bytes): loop structs overlay weight staging area
#define HCAT_OFF 0
#define XS_OFF   16640
#define CT_OFF   23296
#define RED_OFF  31488

// d_ws layout (bytes)
#define WIMG_OFF 0
#define WIMG_BYTES (16 * IMG_HALVES * 2)
#define HX0_OFF WIMG_BYTES
#define HX_WORDS (2 * 16 * 16 * 256)
#define HX1_OFF (HX0_OFF + HX_WORDS * 4)
#define HX_TOTAL_BYTES (2 * HX_WORDS * 4)    // 1 MiB

typedef _Float16 f16x8 __attribute__((ext_vector_type(8)));
typedef float f32x4 __attribute__((ext_vector_type(4)));
typedef unsigned int u32x4 __attribute__((ext_vector_type(4)));

#define PINV(x) asm volatile("" : "+v"(x))

__device__ __forceinline__ void bar_lds() {
  asm volatile("s_waitcnt lgkmcnt(0)" ::: "memory");
  __builtin_amdgcn_s_barrier();
  __builtin_amdgcn_sched_barrier(0);
}

// MALL-routed coherent ops (sc0 sc1), placement-independent (R4..R8-proven)
__device__ __forceinline__ void st_u32_sys(unsigned* p, unsigned v) {
  asm volatile("global_store_dword %0, %1, off sc0 sc1" :: "v"(p), "v"(v) : "memory");
}
// async issue: no waitcnt; consumer pins with vmcnt(0) later
__device__ __forceinline__ void issue4_sys(const unsigned* p, u32x4& a, u32x4& b,
                                           u32x4& c, u32x4& d) {
  asm volatile(
      "global_load_dwordx4 %0, %4, off sc0 sc1\n\t"
      "global_load_dwordx4 %1, %4, off offset:16 sc0 sc1\n\t"
      "global_load_dwordx4 %2, %4, off offset:32 sc0 sc1\n\t"
      "global_load_dwordx4 %3, %4, off offset:48 sc0 sc1"
      : "=&v"(a), "=&v"(b), "=&v"(c), "=&v"(d)
      : "v"(p) : "memory");
}
// blocking reload (retry path)
__device__ __forceinline__ void ld4b_sys(const unsigned* p, u32x4& a, u32x4& b,
                                         u32x4& c, u32x4& d) {
  asm volatile(
      "global_load_dwordx4 %0, %4, off sc0 sc1\n\t"
      "global_load_dwordx4 %1, %4, off offset:16 sc0 sc1\n\t"
      "global_load_dwordx4 %2, %4, off offset:32 sc0 sc1\n\t"
      "global_load_dwordx4 %3, %4, off offset:48 sc0 sc1\n\t"
      "s_waitcnt vmcnt(0)"
      : "=&v"(a), "=&v"(b), "=&v"(c), "=&v"(d)
      : "v"(p) : "memory");
}

__device__ __forceinline__ bool tags_ok(const u32x4& a, const u32x4& b,
                                        const u32x4& c, const u32x4& e, unsigned tg) {
  u32x4 m4 = __builtin_elementwise_min(__builtin_elementwise_min(a, b),
                                       __builtin_elementwise_min(c, e));
  unsigned m = m4.x;
  m = m4.y < m ? m4.y : m;
  m = m4.z < m ? m4.z : m;
  m = m4.w < m ? m4.w : m;
  return (m >> 16) == tg;
}

__device__ __forceinline__ void unpack16(_Float16* d, const u32x4& a, const u32x4& b,
                                         const u32x4& c, const u32x4& e) {
  *(unsigned*)(d + 0)  = (a.x & 0xffffu) | (a.y << 16);
  *(unsigned*)(d + 2)  = (a.z & 0xffffu) | (a.w << 16);
  *(unsigned*)(d + 4)  = (b.x & 0xffffu) | (b.y << 16);
  *(unsigned*)(d + 6)  = (b.z & 0xffffu) | (b.w << 16);
  *(unsigned*)(d + 8)  = (c.x & 0xffffu) | (c.y << 16);
  *(unsigned*)(d + 10) = (c.z & 0xffffu) | (c.w << 16);
  *(unsigned*)(d + 12) = (e.x & 0xffffu) | (e.y << 16);
  *(unsigned*)(d + 14) = (e.z & 0xffffu) | (e.w << 16);
}

// Weight image per block j (halves): W0 [48][W0S] (x cols 0..74, h cols 96..351),
// W1 [48][W1S] (h0 cols 0..255, h1 cols 256..511); row = gate*16+u.
__global__ void prep_wimg(const float* __restrict__ wih0, const float* __restrict__ whh0,
                          const float* __restrict__ wih1, const float* __restrict__ whh1,
                          _Float16* __restrict__ wimg) {
  const int total = 16 * IMG_HALVES;
  for (int i = blockIdx.x * blockDim.x + threadIdx.x; i < total;
       i += gridDim.x * blockDim.x) {
    const int j = i / IMG_HALVES;
    int rem = i - j * IMG_HALVES;
    float val = 0.f;
    if (rem < W0_HALVES) {
      const int row = rem / W0S, k = rem - row * W0S;
      const int gate = row >> 4, u = row & 15;
      const int grow = gate * NH + j * 16 + u;
      if (k < NF) val = wih0[grow * NF + k];
      else if (k >= 96 && k < 352) val = whh0[grow * NH + (k - 96)];
    } else {
      rem -= W0_HALVES;
      const int row = rem / W1S, k = rem - row * W1S;
      const int gate = row >> 4, u = row & 15;
      const int grow = gate * NH + j * 16 + u;
      if (k < 256) val = wih1[grow * NH + k];
      else if (k < 512) val = whh1[grow * NH + (k - 256)];
    }
    wimg[i] = (_Float16)val;
  }
}

__global__ __launch_bounds__(256, 1) void gru_mfma(
    const float* __restrict__ x,
    const float* __restrict__ b_ih0, const float* __restrict__ b_hh0,
    const float* __restrict__ b_ih1, const float* __restrict__ b_hh1,
    const float* __restrict__ w_lin, const float* __restrict__ b_lin,
    const _Float16* __restrict__ wimg,
    unsigned* __restrict__ hx0, unsigned* __restrict__ hx1,
    float* __restrict__ out)
{
  const int tid = threadIdx.x;
  const int bid = blockIdx.x;
  const int gr = (bid & 7) + ((bid >> 7) << 3);
  const int j  = (bid >> 3) & 15;

  __shared__ f16x8 smem8[IMG_HALVES / 8];
  _Float16* Wst  = (_Float16*)smem8;
  _Float16* hcat = (_Float16*)((char*)smem8 + HCAT_OFF);
  _Float16* xs   = (_Float16*)((char*)smem8 + XS_OFF);
  float (*ctile)[64][4] = (float(*)[64][4])((char*)smem8 + CT_OFF);
  float (*red)[17]      = (float(*)[17])((char*)smem8 + RED_OFF);

  int dead = 0, spins = 0;

  // ---- stage weight image ----
  {
    const float4* src = (const float4*)(wimg + (size_t)j * IMG_HALVES);
    float4* dst = (float4*)Wst;
    for (int i = tid; i < IMG_HALVES / 8; i += 256) dst[i] = src[i];
  }

  const int row = tid >> 4, u = tid & 15, gu = j * 16 + u;
  const int wid = tid >> 6, lane = tid & 63;
  const int lrow = lane & 15, lko = (lane >> 4) * 8;

  const float br0 = b_ih0[gu] + b_hh0[gu];
  const float bz0 = b_ih0[NH + gu] + b_hh0[NH + gu];
  const float bnx0 = b_ih0[2 * NH + gu], bnh0 = b_hh0[2 * NH + gu];
  const float br1 = b_ih1[gu] + b_hh1[gu];
  const float bz1 = b_ih1[NH + gu] + b_hh1[NH + gu];
  const float bnx1 = b_ih1[2 * NH + gu], bnh1 = b_hh1[2 * NH + gu];

  __syncthreads();   // Sa

  // ---- hoist loop-invariant B-fragments to VGPRs ----
  _Float16* W0s = Wst;
  _Float16* W1s = Wst + W0_HALVES;
  f16x8 Bw[11], Bn[16];
  if (wid == 0) {            // L0-r (ct0) + L1-nx (ct6, h0-operand)
    const _Float16* wb = W0s + lrow * W0S + lko;
    #pragma unroll
    for (int i = 0; i < 11; ++i) { Bw[i] = *(const f16x8*)(wb + i * 32); PINV(Bw[i]); }
    const _Float16* wn = W1s + (32 + lrow) * W1S + lko;
    #pragma unroll
    for (int i = 0; i < 8; ++i) { Bn[i] = *(const f16x8*)(wn + i * 32); PINV(Bn[i]); }
  } else if (wid == 1) {     // L0-z (ct1) + L1-nh (ct7, h1-operand)
    const _Float16* wb = W0s + (16 + lrow) * W0S + lko;
    #pragma unroll
    for (int i = 0; i < 11; ++i) { Bw[i] = *(const f16x8*)(wb + i * 32); PINV(Bw[i]); }
    const _Float16* wn = W1s + (32 + lrow) * W1S + lko;
    #pragma unroll
    for (int i = 0; i < 8; ++i) { Bn[i] = *(const f16x8*)(wn + (8 + i) * 32); PINV(Bn[i]); }
  } else if (wid == 2) {     // L0-nx (ct2) + L1-r full (ct4)
    const _Float16* wb = W0s + (32 + lrow) * W0S + lko;
    #pragma unroll
    for (int i = 0; i < 3; ++i) { Bw[i] = *(const f16x8*)(wb + i * 32); PINV(Bw[i]); }
    const _Float16* wn = W1s + lrow * W1S + lko;
    #pragma unroll
    for (int i = 0; i < 16; ++i) { Bn[i] = *(const f16x8*)(wn + i * 32); PINV(Bn[i]); }
  } else {                   // L0-nh (ct3) + L1-z full (ct5)
    const _Float16* wb = W0s + (32 + lrow) * W0S + lko;
    #pragma unroll
    for (int i = 0; i < 8; ++i) { Bw[i] = *(const f16x8*)(wb + (3 + i) * 32); PINV(Bw[i]); }
    const _Float16* wn = W1s + (16 + lrow) * W1S + lko;
    #pragma unroll
    for (int i = 0; i < 16; ++i) { Bn[i] = *(const f16x8*)(wn + i * 32); PINV(Bn[i]); }
  }
  __syncthreads();   // Sb: hoist done, weight bytes may be clobbered

  for (int i = tid; i < 16 * HCS; i += 256) hcat[i] = (_Float16)0.f;
  for (int i = tid; i < 2 * 16 * XSS; i += 256) xs[i] = (_Float16)0.f;

  int xr_[5], xc_[5]; bool xv_[5];
  #pragma unroll
  for (int i = 0; i < 5; ++i) {
    const int idx = i * 256 + tid;
    xv_[i] = idx < 16 * NF;
    xr_[i] = xv_[i] ? idx / NF : 0;
    xc_[i] = xv_[i] ? idx % NF : 0;
  }
  const float* __restrict__ xbase = x + (size_t)(gr * 16) * NS * NF;
  #pragma unroll
  for (int i = 0; i < 5; ++i)
    if (xv_[i]) xs[xr_[i] * XSS + xc_[i]] =
        (_Float16)xbase[(size_t)xr_[i] * NS * NF + xc_[i]];

  float h0f = 0.f, h1f = 0.f;
  const int mj = tid & 15, rr = tid >> 4;
  const int chunk = gr * 4096 + rr * 256 + mj * 16;
  __syncthreads();   // Sc

  for (int p = 0; p <= NS; ++p) {
    const int par = p & 1;

    // (1) x prefetch (issue before async gathers so compiler vm-counts help)
    float xf[5];
    if (p + 1 < NS) {
      #pragma unroll
      for (int i = 0; i < 5; ++i)
        if (xv_[i]) xf[i] = xbase[((size_t)xr_[i] * NS + (p + 1)) * NF + xc_[i]];
    }

    // (a) async h1[p-2] gather (published a full phase ago; slot (p-2)&1 = par)
    u32x4 B0, B1, B2, B3;
    if (p >= 2) issue4_sys(hx1 + par * 65536 + chunk, B0, B1, B2, B3);

    // (2) A-fragments: x[p] and h0[p-1]
    const _Float16* __restrict__ xp = xs + par * (16 * XSS) + lrow * XSS + lko;
    const _Float16* __restrict__ hp = hcat + lrow * HCS + lko;
    f16x8 xa0{}, xa1{}, xa2{};
    if (wid != 3) {
      xa0 = *(const f16x8*)(xp);
      xa1 = *(const f16x8*)(xp + 32);
      xa2 = *(const f16x8*)(xp + 64);
    }
    f16x8 hfr0[8];
    #pragma unroll
    for (int kb = 0; kb < 8; ++kb) hfr0[kb] = *(const f16x8*)(hp + kb * 32);

    // (3) pre-barrier MFMA: L0 tiles + h0-parts of L1 tiles
    f32x4 acc45 = {0.f, 0.f, 0.f, 0.f};   // ct4/ct5 partial (wid2/3), carried
    {
      f32x4 accA = {0.f, 0.f, 0.f, 0.f};
      if (wid == 0) {
        accA = __builtin_amdgcn_mfma_f32_16x16x32_f16(xa0, Bw[0], accA, 0, 0, 0);
        accA = __builtin_amdgcn_mfma_f32_16x16x32_f16(xa1, Bw[1], accA, 0, 0, 0);
        accA = __builtin_amdgcn_mfma_f32_16x16x32_f16(xa2, Bw[2], accA, 0, 0, 0);
        #pragma unroll
        for (int kb = 0; kb < 8; ++kb)
          accA = __builtin_amdgcn_mfma_f32_16x16x32_f16(hfr0[kb], Bw[3 + kb], accA, 0, 0, 0);
        *(f32x4*)&ctile[0][lane][0] = accA;
        f32x4 acc6 = {0.f, 0.f, 0.f, 0.f};
        #pragma unroll
        for (int kb = 0; kb < 8; ++kb)
          acc6 = __builtin_amdgcn_mfma_f32_16x16x32_f16(hfr0[kb], Bn[kb], acc6, 0, 0, 0);
        *(f32x4*)&ctile[6][lane][0] = acc6;
      } else if (wid == 1) {
        accA = __builtin_amdgcn_mfma_f32_16x16x32_f16(xa0, Bw[0], accA, 0, 0, 0);
        accA = __builtin_amdgcn_mfma_f32_16x16x32_f16(xa1, Bw[1], accA, 0, 0, 0);
        accA = __builtin_amdgcn_mfma_f32_16x16x32_f16(xa2, Bw[2], accA, 0, 0, 0);
        #pragma unroll
        for (int kb = 0; kb < 8; ++kb)
          accA = __builtin_amdgcn_mfma_f32_16x16x32_f16(hfr0[kb], Bw[3 + kb], accA, 0, 0, 0);
        *(f32x4*)&ctile[1][lane][0] = accA;
      } else if (wid == 2) {
        accA = __builtin_amdgcn_mfma_f32_16x16x32_f16(xa0, Bw[0], accA, 0, 0, 0);
        accA = __builtin_amdgcn_mfma_f32_16x16x32_f16(xa1, Bw[1], accA, 0, 0, 0);
        accA = __builtin_amdgcn_mfma_f32_16x16x32_f16(xa2, Bw[2], accA, 0, 0, 0);
        *(f32x4*)&ctile[2][lane][0] = accA;
        #pragma unroll
        for (int kb = 0; kb < 8; ++kb)
          acc45 = __builtin_amdgcn_mfma_f32_16x16x32_f16(hfr0[kb], Bn[kb], acc45, 0, 0, 0);
      } else {
        #pragma unroll
        for (int kb = 0; kb < 8; ++kb)
          accA = __builtin_amdgcn_mfma_f32_16x16x32_f16(hfr0[kb], Bw[kb], accA, 0, 0, 0);
        *(f32x4*)&ctile[3][lane][0] = accA;
        #pragma unroll
        for (int kb = 0; kb < 8; ++kb)
          acc45 = __builtin_amdgcn_mfma_f32_16x16x32_f16(hfr0[kb], Bn[kb], acc45, 0, 0, 0);
      }
    }

    // (3.5) stage x[p+1]
    if (p + 1 < NS) {
      #pragma unroll
      for (int i = 0; i < 5; ++i)
        if (xv_[i]) xs[((p + 1) & 1) * (16 * XSS) + xr_[i] * XSS + xc_[i]] =
            (_Float16)xf[i];
    }
    bar_lds();   // S1: ct0..3,ct6 ready; hcat/xs(par) reads done

    // (4) h0 gates + publish h0[p] (slot p&1, tag p+1)
    const int li = ((row >> 2) << 4) | u, rg = row & 3;
    if (p < NS) {
      const float ar = ctile[0][li][rg] + br0;
      const float az = ctile[1][li][rg] + bz0;
      const float nx = ctile[2][li][rg] + bnx0;
      const float nh = ctile[3][li][rg] + bnh0;
      const float r = 1.f / (1.f + __expf(-ar));
      const float z = 1.f / (1.f + __expf(-az));
      const float n = tanhf(nx + r * nh);
      h0f = (1.f - z) * n + z * h0f;
      union { _Float16 h; unsigned short s; } c; c.h = (_Float16)h0f;
      st_u32_sys(hx0 + par * 65536 + gr * 4096 + row * 256 + gu,
                 (unsigned)c.s | ((unsigned)(p + 1) << 16));
    }

    // (5) validate h1[p-2] (tag p-1) + unpack into hcat h1-half
    if (p >= 2) {
      asm volatile("s_waitcnt vmcnt(0)"
                   : "+v"(B0), "+v"(B1), "+v"(B2), "+v"(B3) :: "memory");
      while (!tags_ok(B0, B1, B2, B3, (unsigned)(p - 1))) {
        if (++spins > 200000) { dead = 1; break; }
        __builtin_amdgcn_s_sleep(1);
        ld4b_sys(hx1 + par * 65536 + chunk, B0, B1, B2, B3);
      }
      unpack16(hcat + rr * HCS + 256 + mj * 16, B0, B1, B2, B3);
    }
    bar_lds();   // S2: h1[p-2] in hcat

    // (6) post-barrier MFMA: h1-parts of L1 tiles
    {
      const _Float16* hq = hcat + lrow * HCS + 256 + lko;
      if (wid == 1) {
        f16x8 h1r[8];
        #pragma unroll
        for (int kb = 0; kb < 8; ++kb) h1r[kb] = *(const f16x8*)(hq + kb * 32);
        f32x4 a7 = {0.f, 0.f, 0.f, 0.f};
        #pragma unroll
        for (int kb = 0; kb < 8; ++kb)
          a7 = __builtin_amdgcn_mfma_f32_16x16x32_f16(h1r[kb], Bn[kb], a7, 0, 0, 0);
        *(f32x4*)&ctile[7][lane][0] = a7;
      } else if (wid == 2) {
        f16x8 h1r[8];
        #pragma unroll
        for (int kb = 0; kb < 8; ++kb) h1r[kb] = *(const f16x8*)(hq + kb * 32);
        #pragma unroll
        for (int kb = 0; kb < 8; ++kb)
          acc45 = __builtin_amdgcn_mfma_f32_16x16x32_f16(h1r[kb], Bn[8 + kb], acc45, 0, 0, 0);
        *(f32x4*)&ctile[4][lane][0] = acc45;
      } else if (wid == 3) {
        f16x8 h1r[8];
        #pragma unroll
        for (int kb = 0; kb < 8; ++kb) h1r[kb] = *(const f16x8*)(hq + kb * 32);
        #pragma unroll
        for (int kb = 0; kb < 8; ++kb)
          acc45 = __builtin_amdgcn_mfma_f32_16x16x32_f16(h1r[kb], Bn[8 + kb], acc45, 0, 0, 0);
        *(f32x4*)&ctile[5][lane][0] = acc45;
      }
    }

    // (6.5) async h0[p] gather issue (published at (4), age ~0.5 us and growing)
    u32x4 A0, A1, A2, A3;
    if (p < NS) issue4_sys(hx0 + par * 65536 + chunk, A0, A1, A2, A3);
    bar_lds();   // S3: ct4..7 ready

    // (7) h1 gates -> h1[p-1] = f(h0[p-1], h1[p-2]); publish (slot (p-1)&1, tag p)
    if (p >= 1) {
      const float ar = ctile[4][li][rg] + br1;
      const float az = ctile[5][li][rg] + bz1;
      const float nx = ctile[6][li][rg] + bnx1;
      const float nh = ctile[7][li][rg] + bnh1;
      const float r = 1.f / (1.f + __expf(-ar));
      const float z = 1.f / (1.f + __expf(-az));
      const float n = tanhf(nx + r * nh);
      h1f = (1.f - z) * n + z * h1f;
      union { _Float16 h; unsigned short s; } c; c.h = (_Float16)h1f;
      st_u32_sys(hx1 + ((p - 1) & 1) * 65536 + gr * 4096 + row * 256 + gu,
                 (unsigned)c.s | ((unsigned)p << 16));
    }

    // (8) validate h0[p] (tag p+1) + unpack into hcat h0-half
    if (p < NS) {
      asm volatile("s_waitcnt vmcnt(0)"
                   : "+v"(A0), "+v"(A1), "+v"(A2), "+v"(A3) :: "memory");
      while (!tags_ok(A0, A1, A2, A3, (unsigned)(p + 1))) {
        if (++spins > 200000) { dead = 1; break; }
        __builtin_amdgcn_s_sleep(1);
        ld4b_sys(hx0 + par * 65536 + chunk, A0, A1, A2, A3);
      }
      unpack16(hcat + rr * HCS + mj * 16, A0, A1, A2, A3);
    }
    bar_lds();   // S4
  }

  // ---- final: gather h1[NS-1] (slot (NS-1)&1, tag NS), then linear ----
  {
    u32x4 C0, C1, C2, C3;
    const unsigned* src = hx1 + ((NS - 1) & 1) * 65536 + chunk;
    for (;;) {
      ld4b_sys(src, C0, C1, C2, C3);
      if (tags_ok(C0, C1, C2, C3, (unsigned)NS)) break;
      if (++spins > 200000) { dead = 1; break; }
      __builtin_amdgcn_s_sleep(1);
    }
    unpack16(hcat + rr * HCS + 256 + mj * 16, C0, C1, C2, C3);
  }
  __syncthreads();
  {
    float part = 0.f;
    #pragma unroll
    for (int e = 0; e < 16; ++e)
      part += (float)hcat[row * HCS + 256 + u * 16 + e] * w_lin[u * 16 + e];
    red[row][u] = part;
    __syncthreads();
    if (j == 0 && tid < 16) {
      float s = 0.f;
      #pragma unroll
      for (int e = 0; e < 16; ++e) s += red[tid][e];
      out[gr * 16 + tid] = s + b_lin[0];
    }
  }
}

extern "C" void kernel_launch(void* const* d_in, const int* in_sizes, int n_in,
                              void* d_out, int out_size, void* d_ws, size_t ws_size,
                              hipStream_t stream) {
  (void)in_sizes; (void)n_in; (void)out_size; (void)ws_size;
  const float* x     = (const float*)d_in[0];
  const float* w_ih0 = (const float*)d_in[1];
  const float* w_hh0 = (const float*)d_in[2];
  const float* b_ih0 = (const float*)d_in[3];
  const float* b_hh0 = (const float*)d_in[4];
  const float* w_ih1 = (const float*)d_in[5];
  const float* w_hh1 = (const float*)d_in[6];
  const float* b_ih1 = (const float*)d_in[7];
  const float* b_hh1 = (const float*)d_in[8];
  const float* w_lin = (const float*)d_in[9];
  const float* b_lin = (const float*)d_in[10];

  char* ws = (char*)d_ws;
  _Float16* wimg = (_Float16*)(ws + WIMG_OFF);
  unsigned* hx0  = (unsigned*)(ws + HX0_OFF);
  unsigned* hx1  = (unsigned*)(ws + HX1_OFF);

  hipMemsetAsync(ws + HX0_OFF, 0, HX_TOTAL_BYTES, stream);
  prep_wimg<<<1024, 256, 0, stream>>>(w_ih0, w_hh0, w_ih1, w_hh1, wimg);
  gru_mfma<<<256, 256, 0, stream>>>(x, b_ih0, b_hh0, b_ih1, b_hh1,
                                    w_lin, b_lin, wimg, hx0, hx1,
                                    (float*)d_out);
}

// Round 11
// 2372.577 us; speedup vs baseline: 3.1955x; 1.2057x over previous
//
#include <hip/hip_runtime.h>
#include <hip/hip_fp16.h>

// GRU 2-layer, B=256 S=1024 F=75 H=256.
// Round 11: 8 waves/block (512 thr) = 2 waves/SIMD (R10 was 1 wave/SIMD, zero
//  latency hiding). One MFMA tile per wave. Role-split halves run concurrently:
//  tid<256 owns h0 (L0 gates + publish + validate h0[p]); tid>=256 owns h1
//  (validate h1[p-2] + L1 gates + publish). Serial gate/validate chains -> max().
//  Exchange protocol identical to R10 (tagged, split-wait, lgkmcnt-only barriers).

#define NS 1024
#define NF 75
#define NH 256

#define W0S 360   // halves: 96(x pad) + 256(h) + 8 pad
#define W1S 520   // 256(h0) + 256(h1) + 8 pad
#define HCS 520   // hcat row halves: [h0 0..255 | h1 256..511] + pad
#define XSS 104   // 96 + 8 pad

#define W0_HALVES (48 * W0S)                 // 17280
#define W1_HALVES (48 * W1S)                 // 24960
#define IMG_HALVES (W0_HALVES + W1_HALVES)   // 42240 halves = 84480 B

// shared aliasing offsets (bytes)
#define HCAT_OFF 0
#define XS_OFF   16640
#define CT_OFF   23296
#define RED_OFF  31488

// d_ws layout (bytes)
#define WIMG_OFF 0
#define WIMG_BYTES (16 * IMG_HALVES * 2)
#define HX0_OFF WIMG_BYTES
#define HX_WORDS (2 * 16 * 16 * 256)
#define HX1_OFF (HX0_OFF + HX_WORDS * 4)
#define HX_TOTAL_BYTES (2 * HX_WORDS * 4)    // 1 MiB

typedef _Float16 f16x8 __attribute__((ext_vector_type(8)));
typedef float f32x4 __attribute__((ext_vector_type(4)));
typedef unsigned int u32x4 __attribute__((ext_vector_type(4)));

#define PINV(x) asm volatile("" : "+v"(x))

__device__ __forceinline__ void bar_lds() {
  asm volatile("s_waitcnt lgkmcnt(0)" ::: "memory");
  __builtin_amdgcn_s_barrier();
  __builtin_amdgcn_sched_barrier(0);
}

// MALL-routed coherent ops (sc0 sc1), placement-independent (R4..R10-proven)
__device__ __forceinline__ void st_u32_sys(unsigned* p, unsigned v) {
  asm volatile("global_store_dword %0, %1, off sc0 sc1" :: "v"(p), "v"(v) : "memory");
}
__device__ __forceinline__ void issue4_sys(const unsigned* p, u32x4& a, u32x4& b,
                                           u32x4& c, u32x4& d) {
  asm volatile(
      "global_load_dwordx4 %0, %4, off sc0 sc1\n\t"
      "global_load_dwordx4 %1, %4, off offset:16 sc0 sc1\n\t"
      "global_load_dwordx4 %2, %4, off offset:32 sc0 sc1\n\t"
      "global_load_dwordx4 %3, %4, off offset:48 sc0 sc1"
      : "=&v"(a), "=&v"(b), "=&v"(c), "=&v"(d)
      : "v"(p) : "memory");
}
__device__ __forceinline__ void ld4b_sys(const unsigned* p, u32x4& a, u32x4& b,
                                         u32x4& c, u32x4& d) {
  asm volatile(
      "global_load_dwordx4 %0, %4, off sc0 sc1\n\t"
      "global_load_dwordx4 %1, %4, off offset:16 sc0 sc1\n\t"
      "global_load_dwordx4 %2, %4, off offset:32 sc0 sc1\n\t"
      "global_load_dwordx4 %3, %4, off offset:48 sc0 sc1\n\t"
      "s_waitcnt vmcnt(0)"
      : "=&v"(a), "=&v"(b), "=&v"(c), "=&v"(d)
      : "v"(p) : "memory");
}

__device__ __forceinline__ bool tags_ok(const u32x4& a, const u32x4& b,
                                        const u32x4& c, const u32x4& e, unsigned tg) {
  u32x4 m4 = __builtin_elementwise_min(__builtin_elementwise_min(a, b),
                                       __builtin_elementwise_min(c, e));
  unsigned m = m4.x;
  m = m4.y < m ? m4.y : m;
  m = m4.z < m ? m4.z : m;
  m = m4.w < m ? m4.w : m;
  return (m >> 16) == tg;
}

__device__ __forceinline__ void unpack16(_Float16* d, const u32x4& a, const u32x4& b,
                                         const u32x4& c, const u32x4& e) {
  *(unsigned*)(d + 0)  = (a.x & 0xffffu) | (a.y << 16);
  *(unsigned*)(d + 2)  = (a.z & 0xffffu) | (a.w << 16);
  *(unsigned*)(d + 4)  = (b.x & 0xffffu) | (b.y << 16);
  *(unsigned*)(d + 6)  = (b.z & 0xffffu) | (b.w << 16);
  *(unsigned*)(d + 8)  = (c.x & 0xffffu) | (c.y << 16);
  *(unsigned*)(d + 10) = (c.z & 0xffffu) | (c.w << 16);
  *(unsigned*)(d + 12) = (e.x & 0xffffu) | (e.y << 16);
  *(unsigned*)(d + 14) = (e.z & 0xffffu) | (e.w << 16);
}

// Weight image per block j (halves): W0 [48][W0S] (x cols 0..74, h cols 96..351),
// W1 [48][W1S] (h0 cols 0..255, h1 cols 256..511); row = gate*16+u.
__global__ void prep_wimg(const float* __restrict__ wih0, const float* __restrict__ whh0,
                          const float* __restrict__ wih1, const float* __restrict__ whh1,
                          _Float16* __restrict__ wimg) {
  const int total = 16 * IMG_HALVES;
  for (int i = blockIdx.x * blockDim.x + threadIdx.x; i < total;
       i += gridDim.x * blockDim.x) {
    const int j = i / IMG_HALVES;
    int rem = i - j * IMG_HALVES;
    float val = 0.f;
    if (rem < W0_HALVES) {
      const int row = rem / W0S, k = rem - row * W0S;
      const int gate = row >> 4, u = row & 15;
      const int grow = gate * NH + j * 16 + u;
      if (k < NF) val = wih0[grow * NF + k];
      else if (k >= 96 && k < 352) val = whh0[grow * NH + (k - 96)];
    } else {
      rem -= W0_HALVES;
      const int row = rem / W1S, k = rem - row * W1S;
      const int gate = row >> 4, u = row & 15;
      const int grow = gate * NH + j * 16 + u;
      if (k < 256) val = wih1[grow * NH + k];
      else if (k < 512) val = whh1[grow * NH + (k - 256)];
    }
    wimg[i] = (_Float16)val;
  }
}

__global__ __launch_bounds__(512, 1) void gru_mfma(
    const float* __restrict__ x,
    const float* __restrict__ b_ih0, const float* __restrict__ b_hh0,
    const float* __restrict__ b_ih1, const float* __restrict__ b_hh1,
    const float* __restrict__ w_lin, const float* __restrict__ b_lin,
    const _Float16* __restrict__ wimg,
    unsigned* __restrict__ hx0, unsigned* __restrict__ hx1,
    float* __restrict__ out)
{
  const int tid = threadIdx.x;
  const int bid = blockIdx.x;
  const int gr = (bid & 7) + ((bid >> 7) << 3);
  const int j  = (bid >> 3) & 15;

  __shared__ f16x8 smem8[IMG_HALVES / 8];
  _Float16* Wst  = (_Float16*)smem8;
  _Float16* hcat = (_Float16*)((char*)smem8 + HCAT_OFF);
  _Float16* xs   = (_Float16*)((char*)smem8 + XS_OFF);
  float (*ctile)[64][4] = (float(*)[64][4])((char*)smem8 + CT_OFF);
  float (*red)[17]      = (float(*)[17])((char*)smem8 + RED_OFF);

  int dead = 0, spins = 0;

  // ---- stage weight image ----
  {
    const float4* src = (const float4*)(wimg + (size_t)j * IMG_HALVES);
    float4* dst = (float4*)Wst;
    for (int i = tid; i < IMG_HALVES / 8; i += 512) dst[i] = src[i];
  }

  const int t8 = tid & 255;
  const int row = t8 >> 4, u = t8 & 15, gu = j * 16 + u;
  const int wid = tid >> 6, lane = tid & 63;
  const int lrow = lane & 15, lko = (lane >> 4) * 8;
  const int chunk = gr * 4096 + row * 256 + u * 16;

  float gbr, gbz, gbnx, gbnh;
  if (tid < 256) {
    gbr  = b_ih0[gu] + b_hh0[gu];
    gbz  = b_ih0[NH + gu] + b_hh0[NH + gu];
    gbnx = b_ih0[2 * NH + gu];
    gbnh = b_hh0[2 * NH + gu];
  } else {
    gbr  = b_ih1[gu] + b_hh1[gu];
    gbz  = b_ih1[NH + gu] + b_hh1[NH + gu];
    gbnx = b_ih1[2 * NH + gu];
    gbnh = b_hh1[2 * NH + gu];
  }

  __syncthreads();   // Sa: weights staged

  // ---- hoist per-wave B-fragments (one tile per wave) ----
  _Float16* W0s = Wst;
  _Float16* W1s = Wst + W0_HALVES;
  f16x8 Bf[16];
  if (wid == 0) {            // ct0 = L0-r
    const _Float16* wb = W0s + lrow * W0S + lko;
    #pragma unroll
    for (int i = 0; i < 11; ++i) { Bf[i] = *(const f16x8*)(wb + i * 32); PINV(Bf[i]); }
  } else if (wid == 1) {     // ct1 = L0-z
    const _Float16* wb = W0s + (16 + lrow) * W0S + lko;
    #pragma unroll
    for (int i = 0; i < 11; ++i) { Bf[i] = *(const f16x8*)(wb + i * 32); PINV(Bf[i]); }
  } else if (wid == 2) {     // ct2 = L0-nx (x-part only)
    const _Float16* wb = W0s + (32 + lrow) * W0S + lko;
    #pragma unroll
    for (int i = 0; i < 3; ++i) { Bf[i] = *(const f16x8*)(wb + i * 32); PINV(Bf[i]); }
  } else if (wid == 3) {     // ct3 = L0-nh (h-part)
    const _Float16* wb = W0s + (32 + lrow) * W0S + lko;
    #pragma unroll
    for (int i = 0; i < 8; ++i) { Bf[i] = *(const f16x8*)(wb + (3 + i) * 32); PINV(Bf[i]); }
  } else if (wid == 4) {     // ct4 = L1-r (h0 cols then h1 cols)
    const _Float16* wn = W1s + lrow * W1S + lko;
    #pragma unroll
    for (int i = 0; i < 16; ++i) { Bf[i] = *(const f16x8*)(wn + i * 32); PINV(Bf[i]); }
  } else if (wid == 5) {     // ct5 = L1-z
    const _Float16* wn = W1s + (16 + lrow) * W1S + lko;
    #pragma unroll
    for (int i = 0; i < 16; ++i) { Bf[i] = *(const f16x8*)(wn + i * 32); PINV(Bf[i]); }
  } else if (wid == 6) {     // ct6 = L1-nx (h0 cols)
    const _Float16* wn = W1s + (32 + lrow) * W1S + lko;
    #pragma unroll
    for (int i = 0; i < 8; ++i) { Bf[i] = *(const f16x8*)(wn + i * 32); PINV(Bf[i]); }
  } else {                   // ct7 = L1-nh (h1 cols)
    const _Float16* wn = W1s + (32 + lrow) * W1S + lko;
    #pragma unroll
    for (int i = 0; i < 8; ++i) { Bf[i] = *(const f16x8*)(wn + (8 + i) * 32); PINV(Bf[i]); }
  }
  __syncthreads();   // Sb: hoist done, weight bytes may be clobbered

  for (int i = tid; i < 16 * HCS; i += 512) hcat[i] = (_Float16)0.f;
  for (int i = tid; i < 2 * 16 * XSS; i += 512) xs[i] = (_Float16)0.f;

  int xr_[3], xc_[3]; bool xv_[3];
  #pragma unroll
  for (int i = 0; i < 3; ++i) {
    const int idx = i * 512 + tid;
    xv_[i] = idx < 16 * NF;
    xr_[i] = xv_[i] ? idx / NF : 0;
    xc_[i] = xv_[i] ? idx % NF : 0;
  }
  const float* __restrict__ xbase = x + (size_t)(gr * 16) * NS * NF;
  #pragma unroll
  for (int i = 0; i < 3; ++i)
    if (xv_[i]) xs[xr_[i] * XSS + xc_[i]] =
        (_Float16)xbase[(size_t)xr_[i] * NS * NF + xc_[i]];

  float h0f = 0.f, h1f = 0.f;
  __syncthreads();   // Sc

  for (int p = 0; p <= NS; ++p) {
    const int par = p & 1;

    // (1) x prefetch
    float xf[3];
    if (p + 1 < NS) {
      #pragma unroll
      for (int i = 0; i < 3; ++i)
        if (xv_[i]) xf[i] = xbase[((size_t)xr_[i] * NS + (p + 1)) * NF + xc_[i]];
    }

    // (a) half1: async h1[p-2] gather (published a full phase ago)
    u32x4 G0, G1, G2, G3;
    if (tid >= 256 && p >= 2)
      issue4_sys(hx1 + par * 65536 + chunk, G0, G1, G2, G3);

    // (2)+(3) per-wave A-fragments + pre-barrier MFMAs
    const _Float16* __restrict__ xp = xs + par * (16 * XSS) + lrow * XSS + lko;
    const _Float16* __restrict__ hp = hcat + lrow * HCS + lko;
    f32x4 acc45 = {0.f, 0.f, 0.f, 0.f};   // wid4/5 carried across S2
    if (wid <= 1) {
      f16x8 xa0 = *(const f16x8*)(xp);
      f16x8 xa1 = *(const f16x8*)(xp + 32);
      f16x8 xa2 = *(const f16x8*)(xp + 64);
      f16x8 hfr[8];
      #pragma unroll
      for (int kb = 0; kb < 8; ++kb) hfr[kb] = *(const f16x8*)(hp + kb * 32);
      f32x4 a = {0.f, 0.f, 0.f, 0.f};
      a = __builtin_amdgcn_mfma_f32_16x16x32_f16(xa0, Bf[0], a, 0, 0, 0);
      a = __builtin_amdgcn_mfma_f32_16x16x32_f16(xa1, Bf[1], a, 0, 0, 0);
      a = __builtin_amdgcn_mfma_f32_16x16x32_f16(xa2, Bf[2], a, 0, 0, 0);
      #pragma unroll
      for (int kb = 0; kb < 8; ++kb)
        a = __builtin_amdgcn_mfma_f32_16x16x32_f16(hfr[kb], Bf[3 + kb], a, 0, 0, 0);
      *(f32x4*)&ctile[wid][lane][0] = a;
    } else if (wid == 2) {
      f16x8 xa0 = *(const f16x8*)(xp);
      f16x8 xa1 = *(const f16x8*)(xp + 32);
      f16x8 xa2 = *(const f16x8*)(xp + 64);
      f32x4 a = {0.f, 0.f, 0.f, 0.f};
      a = __builtin_amdgcn_mfma_f32_16x16x32_f16(xa0, Bf[0], a, 0, 0, 0);
      a = __builtin_amdgcn_mfma_f32_16x16x32_f16(xa1, Bf[1], a, 0, 0, 0);
      a = __builtin_amdgcn_mfma_f32_16x16x32_f16(xa2, Bf[2], a, 0, 0, 0);
      *(f32x4*)&ctile[2][lane][0] = a;
    } else if (wid == 3) {
      f16x8 hfr[8];
      #pragma unroll
      for (int kb = 0; kb < 8; ++kb) hfr[kb] = *(const f16x8*)(hp + kb * 32);
      f32x4 a = {0.f, 0.f, 0.f, 0.f};
      #pragma unroll
      for (int kb = 0; kb < 8; ++kb)
        a = __builtin_amdgcn_mfma_f32_16x16x32_f16(hfr[kb], Bf[kb], a, 0, 0, 0);
      *(f32x4*)&ctile[3][lane][0] = a;
    } else if (wid == 4 || wid == 5) {
      f16x8 hfr[8];
      #pragma unroll
      for (int kb = 0; kb < 8; ++kb) hfr[kb] = *(const f16x8*)(hp + kb * 32);
      #pragma unroll
      for (int kb = 0; kb < 8; ++kb)
        acc45 = __builtin_amdgcn_mfma_f32_16x16x32_f16(hfr[kb], Bf[kb], acc45, 0, 0, 0);
    } else if (wid == 6) {
      f16x8 hfr[8];
      #pragma unroll
      for (int kb = 0; kb < 8; ++kb) hfr[kb] = *(const f16x8*)(hp + kb * 32);
      f32x4 a = {0.f, 0.f, 0.f, 0.f};
      #pragma unroll
      for (int kb = 0; kb < 8; ++kb)
        a = __builtin_amdgcn_mfma_f32_16x16x32_f16(hfr[kb], Bf[kb], a, 0, 0, 0);
      *(f32x4*)&ctile[6][lane][0] = a;
    }
    // wid7: no pre-barrier MFMA

    // (3.5) stage x[p+1]
    if (p + 1 < NS) {
      #pragma unroll
      for (int i = 0; i < 3; ++i)
        if (xv_[i]) xs[((p + 1) & 1) * (16 * XSS) + xr_[i] * XSS + xc_[i]] =
            (_Float16)xf[i];
    }
    bar_lds();   // S1: ct0..3,ct6 ready; hcat/xs(par) reads done

    // (4) CONCURRENT: half0 = L0 gates + publish h0[p]; half1 = validate h1[p-2]
    const int li = ((row >> 2) << 4) | u, rg = row & 3;
    if (tid < 256) {
      if (p < NS) {
        const float ar = ctile[0][li][rg] + gbr;
        const float az = ctile[1][li][rg] + gbz;
        const float nx = ctile[2][li][rg] + gbnx;
        const float nh = ctile[3][li][rg] + gbnh;
        const float r = 1.f / (1.f + __expf(-ar));
        const float z = 1.f / (1.f + __expf(-az));
        const float n = tanhf(nx + r * nh);
        h0f = (1.f - z) * n + z * h0f;
        union { _Float16 h; unsigned short s; } c; c.h = (_Float16)h0f;
        st_u32_sys(hx0 + par * 65536 + gr * 4096 + row * 256 + gu,
                   (unsigned)c.s | ((unsigned)(p + 1) << 16));
      }
    } else {
      if (p >= 2) {
        asm volatile("s_waitcnt vmcnt(0)"
                     : "+v"(G0), "+v"(G1), "+v"(G2), "+v"(G3) :: "memory");
        while (!tags_ok(G0, G1, G2, G3, (unsigned)(p - 1))) {
          if (++spins > 200000) { dead = 1; break; }
          __builtin_amdgcn_s_sleep(1);
          ld4b_sys(hx1 + par * 65536 + chunk, G0, G1, G2, G3);
        }
        unpack16(hcat + row * HCS + 256 + u * 16, G0, G1, G2, G3);
      }
    }
    bar_lds();   // S2: h1[p-2] in hcat; h0[p] published

    // (6) half0: async h0[p] gather; waves 4/5/7: h1-part MFMAs
    u32x4 A0, A1, A2, A3;
    if (tid < 256 && p < NS)
      issue4_sys(hx0 + par * 65536 + chunk, A0, A1, A2, A3);
    if (wid == 4 || wid == 5) {
      const _Float16* hq = hcat + lrow * HCS + 256 + lko;
      f16x8 h1r[8];
      #pragma unroll
      for (int kb = 0; kb < 8; ++kb) h1r[kb] = *(const f16x8*)(hq + kb * 32);
      #pragma unroll
      for (int kb = 0; kb < 8; ++kb)
        acc45 = __builtin_amdgcn_mfma_f32_16x16x32_f16(h1r[kb], Bf[8 + kb], acc45, 0, 0, 0);
      *(f32x4*)&ctile[wid][lane][0] = acc45;
    } else if (wid == 7) {
      const _Float16* hq = hcat + lrow * HCS + 256 + lko;
      f16x8 h1r[8];
      #pragma unroll
      for (int kb = 0; kb < 8; ++kb) h1r[kb] = *(const f16x8*)(hq + kb * 32);
      f32x4 a = {0.f, 0.f, 0.f, 0.f};
      #pragma unroll
      for (int kb = 0; kb < 8; ++kb)
        a = __builtin_amdgcn_mfma_f32_16x16x32_f16(h1r[kb], Bf[kb], a, 0, 0, 0);
      *(f32x4*)&ctile[7][lane][0] = a;
    }
    bar_lds();   // S3: ct4..7 ready

    // (7)/(8) CONCURRENT: half1 = L1 gates + publish h1[p-1]; half0 = validate h0[p]
    if (tid >= 256) {
      if (p >= 1) {
        const float ar = ctile[4][li][rg] + gbr;
        const float az = ctile[5][li][rg] + gbz;
        const float nx = ctile[6][li][rg] + gbnx;
        const float nh = ctile[7][li][rg] + gbnh;
        const float r = 1.f / (1.f + __expf(-ar));
        const float z = 1.f / (1.f + __expf(-az));
        const float n = tanhf(nx + r * nh);
        h1f = (1.f - z) * n + z * h1f;
        union { _Float16 h; unsigned short s; } c; c.h = (_Float16)h1f;
        st_u32_sys(hx1 + ((p - 1) & 1) * 65536 + gr * 4096 + row * 256 + gu,
                   (unsigned)c.s | ((unsigned)p << 16));
      }
    } else {
      if (p < NS) {
        asm volatile("s_waitcnt vmcnt(0)"
                     : "+v"(A0), "+v"(A1), "+v"(A2), "+v"(A3) :: "memory");
        while (!tags_ok(A0, A1, A2, A3, (unsigned)(p + 1))) {
          if (++spins > 200000) { dead = 1; break; }
          __builtin_amdgcn_s_sleep(1);
          ld4b_sys(hx0 + par * 65536 + chunk, A0, A1, A2, A3);
        }
        unpack16(hcat + row * HCS + u * 16, A0, A1, A2, A3);
      }
    }
    bar_lds();   // S4
  }

  // ---- final: half1 gathers h1[NS-1] (slot (NS-1)&1, tag NS) ----
  if (tid >= 256) {
    u32x4 C0, C1, C2, C3;
    const unsigned* src = hx1 + ((NS - 1) & 1) * 65536 + chunk;
    for (;;) {
      ld4b_sys(src, C0, C1, C2, C3);
      if (tags_ok(C0, C1, C2, C3, (unsigned)NS)) break;
      if (++spins > 200000) { dead = 1; break; }
      __builtin_amdgcn_s_sleep(1);
    }
    unpack16(hcat + row * HCS + 256 + u * 16, C0, C1, C2, C3);
  }
  __syncthreads();
  if (tid < 256) {
    float part = 0.f;
    #pragma unroll
    for (int e = 0; e < 16; ++e)
      part += (float)hcat[row * HCS + 256 + u * 16 + e] * w_lin[u * 16 + e];
    red[row][u] = part;
  }
  __syncthreads();
  if (j == 0 && tid < 16) {
    float s = 0.f;
    #pragma unroll
    for (int e = 0; e < 16; ++e) s += red[tid][e];
    out[gr * 16 + tid] = s + b_lin[0];
  }
}

extern "C" void kernel_launch(void* const* d_in, const int* in_sizes, int n_in,
                              void* d_out, int out_size, void* d_ws, size_t ws_size,
                              hipStream_t stream) {
  (void)in_sizes; (void)n_in; (void)out_size; (void)ws_size;
  const float* x     = (const float*)d_in[0];
  const float* w_ih0 = (const float*)d_in[1];
  const float* w_hh0 = (const float*)d_in[2];
  const float* b_ih0 = (const float*)d_in[3];
  const float* b_hh0 = (const float*)d_in[4];
  const float* w_ih1 = (const float*)d_in[5];
  const float* w_hh1 = (const float*)d_in[6];
  const float* b_ih1 = (const float*)d_in[7];
  const float* b_hh1 = (const float*)d_in[8];
  const float* w_lin = (const float*)d_in[9];
  const float* b_lin = (const float*)d_in[10];

  char* ws = (char*)d_ws;
  _Float16* wimg = (_Float16*)(ws + WIMG_OFF);
  unsigned* hx0  = (unsigned*)(ws + HX0_OFF);
  unsigned* hx1  = (unsigned*)(ws + HX1_OFF);

  hipMemsetAsync(ws + HX0_OFF, 0, HX_TOTAL_BYTES, stream);
  prep_wimg<<<1024, 256, 0, stream>>>(w_ih0, w_hh0, w_ih1, w_hh1, wimg);
  gru_mfma<<<256, 512, 0, stream>>>(x, b_ih0, b_hh0, b_ih1, b_hh1,
                                    w_lin, b_lin, wimg, hx0, hx1,
                                    (float*)d_out);
}